// Round 3
// baseline (1227.414 us; speedup 1.0000x reference)
//
#include <hip/hip_runtime.h>

// IntegratedNCA: 10 steps of {sobel-perceive -> MLP(112->128->16) -> residual -> life gate}
// B=16, C=16, H=W=128, WDIM=64, HID=128.
// R3 changes vs R2:
//  - hh[128]-resident formulation: per channel c, compute {x,gx,gy} from the LDS tile and
//    immediately accumulate into all 128 hidden units. No long-lived inp[48] for the
//    compiler to sink/rematerialize (R2: VGPR=52, sobel re-done per h0 chunk).
//  - Phase 2 (relu + 128->16) fully unrolled: static hh[] indexing, stays in VGPRs.
//  - W1 pre-packed as W1p[c][{x,gx,gy}][128] -> contiguous wave-uniform s_loads per c.
//  - Residual/gate re-read x from LDS tile (stable after barrier) instead of saving regs.

#define CCH   16
#define WDIM  64
#define HID   128
#define BATCH 16
#define HH    128
#define WWID  128
#define KIN   48           // 3*C
#define NIN   112          // 3*C + WDIM
#define TS    16
#define HALO  18
#define STEPS 10

// Prep: per-batch folded bias + weight re-layouts.
__global__ __launch_bounds__(256) void nca_prep_kernel(
    const float* __restrict__ W1, const float* __restrict__ b1,
    const float* __restrict__ w,  const float* __restrict__ W2,
    float* __restrict__ biasw, float* __restrict__ W1p, float* __restrict__ W2t)
{
    const int t = threadIdx.x;
    // W1p[(c*3+j)*HID + n] = W1[n*NIN + j*CCH + c]   (c in [0,16), j in {x,gx,gy}, n in [0,128))
    for (int i = t; i < KIN * HID; i += 256) {
        int cj = i / HID, n = i % HID;
        int c = cj / 3, j = cj % 3;
        W1p[i] = W1[n * NIN + j * CCH + c];
    }
    // W2t[n][c] = W2[c][n]   (128 x 16)
    for (int i = t; i < HID * CCH; i += 256) {
        int n = i / CCH, c = i % CCH;
        W2t[n * CCH + c] = W2[c * HID + n];
    }
    // biasw[b][n] = b1[n] + sum_j W1[n][48+j] * w[b][j]
    for (int i = t; i < BATCH * HID; i += 256) {
        int b = i / HID, n = i % HID;
        float acc = b1[n];
        const float* wrow  = w  + b * WDIM;
        const float* W1row = W1 + n * NIN + KIN;
        #pragma unroll
        for (int j = 0; j < WDIM; ++j) acc = fmaf(W1row[j], wrow[j], acc);
        biasw[i] = acc;
    }
}

__global__ __launch_bounds__(256, 2) void nca_step_kernel(
    const float* __restrict__ xin, float* __restrict__ xout,
    const float* __restrict__ W1p, const float* __restrict__ W2t,
    const float* __restrict__ b2, const float* __restrict__ biasw)
{
    __shared__ float tile[CCH][HALO][HALO];

    const int b   = blockIdx.z;
    const int ty0 = blockIdx.y * TS;
    const int tx0 = blockIdx.x * TS;
    const int tid = threadIdx.x;

    // ---- stage x tile + halo (zero-padded; safe for conv and for life-maxpool vs >0.1) ----
    const float* xb = xin + b * CCH * HH * WWID;
    for (int idx = tid; idx < CCH * HALO * HALO; idx += 256) {
        int c  = idx / (HALO * HALO);
        int r  = idx % (HALO * HALO);
        int ly = r / HALO, lx = r % HALO;
        int gy = ty0 + ly - 1, gx = tx0 + lx - 1;
        float v = 0.f;
        if (gy >= 0 && gy < HH && gx >= 0 && gx < WWID)
            v = xb[c * HH * WWID + gy * WWID + gx];
        tile[c][ly][lx] = v;
    }
    __syncthreads();

    const int ty = tid >> 4, tx = tid & 15;
    const int ly = ty + 1,  lx = tx + 1;

    // ---- pre_life: 3x3 max of channel 3 > 0.1 ----
    bool pre_life;
    {
        float a0 = tile[3][ly-1][lx-1], a1 = tile[3][ly-1][lx], a2 = tile[3][ly-1][lx+1];
        float a3 = tile[3][ly  ][lx-1], a4 = tile[3][ly  ][lx], a5 = tile[3][ly  ][lx+1];
        float a6 = tile[3][ly+1][lx-1], a7 = tile[3][ly+1][lx], a8 = tile[3][ly+1][lx+1];
        float m = fmaxf(fmaxf(fmaxf(a0, a1), fmaxf(a2, a3)),
                        fmaxf(fmaxf(a4, a5), fmaxf(a6, fmaxf(a7, a8))));
        pre_life = (m > 0.1f);
    }

    // ---- phase 1: hh[n] = biasw[b][n] + sum_c (x*W1p[c][0][n] + gx*W1p[c][1][n] + gy*W1p[c][2][n]) ----
    float hh[HID];
    const float* biasb = biasw + b * HID;
    #pragma unroll
    for (int n = 0; n < HID; ++n) hh[n] = biasb[n];       // uniform -> s_load

    #pragma unroll 1                    // keep the 400-instr body I-cache resident
    for (int c = 0; c < CCH; ++c) {
        float x_mm = tile[c][ly-1][lx-1], x_m0 = tile[c][ly-1][lx], x_mp = tile[c][ly-1][lx+1];
        float x_0m = tile[c][ly  ][lx-1], x_00 = tile[c][ly  ][lx], x_0p = tile[c][ly  ][lx+1];
        float x_pm = tile[c][ly+1][lx-1], x_p0 = tile[c][ly+1][lx], x_pp = tile[c][ly+1][lx+1];
        // cross-correlation (XLA conv semantics, no kernel flip)
        float gxv = (x_mp - x_mm) + 2.f * (x_0p - x_0m) + (x_pp - x_pm);  // sobel_x
        float gyv = (x_pm - x_mm) + 2.f * (x_p0 - x_m0) + (x_pp - x_mp);  // sobel_y
        const float* wp = W1p + c * (3 * HID);            // uniform base, contiguous 384 floats
        #pragma unroll
        for (int n = 0; n < HID; ++n) {
            float t0 = fmaf(x_00, wp[n],           hh[n]);
            float t1 = fmaf(gxv,  wp[HID + n],     t0);
            hh[n]    = fmaf(gyv,  wp[2 * HID + n], t1);
        }
    }

    // ---- phase 2: ds = W2t^T relu(hh) + b2  (fully unrolled: static hh indexing) ----
    float ds[CCH];
    #pragma unroll
    for (int c = 0; c < CCH; ++c) ds[c] = b2[c];          // uniform -> s_load
    #pragma unroll
    for (int n = 0; n < HID; ++n) {
        float hv = fmaxf(hh[n], 0.f);
        const float* w2row = W2t + n * CCH;               // uniform, contiguous 16
        #pragma unroll
        for (int c = 0; c < CCH; ++c)
            ds[c] = fmaf(hv, w2row[c], ds[c]);
    }

    // ---- residual + life gate, store (x re-read from stable LDS tile) ----
    float new3  = tile[3][ly][lx] + ds[3];
    float alive = ((new3 > 0.1f) && pre_life) ? 1.f : 0.f;
    float* ob = xout + b * CCH * HH * WWID;
    const int gy = ty0 + ty, gx = tx0 + tx;
    #pragma unroll
    for (int c = 0; c < CCH; ++c) {
        float nv = tile[c][ly][lx] + ds[c];
        ob[c * HH * WWID + gy * WWID + gx] = nv * alive;
    }
}

extern "C" void kernel_launch(void* const* d_in, const int* in_sizes, int n_in,
                              void* d_out, int out_size, void* d_ws, size_t ws_size,
                              hipStream_t stream) {
    const float* x   = (const float*)d_in[0];
    const float* w   = (const float*)d_in[1];
    const float* W1  = (const float*)d_in[2];
    const float* b1  = (const float*)d_in[3];
    const float* W2  = (const float*)d_in[4];
    const float* b2  = (const float*)d_in[5];
    // d_in[6], d_in[7]: sobel kernels (fixed values, hard-coded); d_in[8]: steps (=10)
    float* out = (float*)d_out;

    float* ws0   = (float*)d_ws;                       // 16 MB ping-pong buffer
    float* biasw = ws0 + BATCH * CCH * HH * WWID;      // 2048 floats
    float* W1p   = biasw + BATCH * HID;                // 6144 floats
    float* W2t   = W1p + KIN * HID;                    // 2048 floats

    nca_prep_kernel<<<1, 256, 0, stream>>>(W1, b1, w, W2, biasw, W1p, W2t);

    dim3 grid(WWID / TS, HH / TS, BATCH);
    for (int s = 0; s < STEPS; ++s) {
        // dst alternates so that step STEPS-1 writes d_out
        float* dst = (((STEPS - 1 - s) & 1) == 0) ? out : ws0;
        const float* src = (s == 0) ? x
                         : ((((STEPS - s) & 1) == 0) ? (const float*)out : (const float*)ws0);
        nca_step_kernel<<<grid, 256, 0, stream>>>(src, dst, W1p, W2t, b2, biasw);
    }
}